// Round 1
// baseline (562.753 us; speedup 1.0000x reference)
//
#include <hip/hip_runtime.h>

#define IMG_H 4200
#define IMG_W 3200
#define HF 84
#define WF 64
#define NB 8
// tiles = 8*84*64 = 43008

// Kernel 1: 50x50 stride-50 VALID conv, 1 -> 2 channels.
// One wave per output tile; 4 waves (256 threads) per block.
__global__ __launch_bounds__(256) void conv1_kernel(
    const float* __restrict__ X, const float* __restrict__ cw,
    const float* __restrict__ cb, float* __restrict__ feats /* [N][HF][WF] float2 */) {
    __shared__ float4 wlds[1250];  // (w0[2e], w0[2e+1], w1[2e], w1[2e+1])
    const int tid = threadIdx.x;
    for (int e = tid; e < 1250; e += 256) {
        wlds[e] = make_float4(cw[2 * e], cw[2 * e + 1], cw[2500 + 2 * e], cw[2500 + 2 * e + 1]);
    }
    __syncthreads();
    const int wave = tid >> 6;
    const int lane = tid & 63;
    const int t = blockIdx.x * 4 + wave;  // tile id = n*HF*WF + i*WF + j
    const int j = t % WF;
    const int i = (t / WF) % HF;
    const int n = t / (WF * HF);
    const float* base = X + ((size_t)n * IMG_H + (size_t)i * 50) * IMG_W + j * 50;
    float acc0 = 0.f, acc1 = 0.f;
#pragma unroll
    for (int it = 0; it < 20; ++it) {
        int e2 = it * 64 + lane;            // float2 index within tile, [0,1250)
        if (e2 < 1250) {
            int ky = e2 / 25;               // row in 50x50 window
            int kx = (e2 - ky * 25) * 2;    // even column
            const float2 x = *(const float2*)(base + (size_t)ky * IMG_W + kx);
            float4 w = wlds[e2];
            acc0 = fmaf(x.x, w.x, fmaf(x.y, w.y, acc0));
            acc1 = fmaf(x.x, w.z, fmaf(x.y, w.w, acc1));
        }
    }
#pragma unroll
    for (int off = 32; off; off >>= 1) {
        acc0 += __shfl_down(acc0, off, 64);
        acc1 += __shfl_down(acc1, off, 64);
    }
    if (lane == 0) {
        ((float2*)feats)[t] = make_float2(acc0 + cb[0], acc1 + cb[1]);
    }
}

// Kernel 2: 3x3 SAME convs (36-ch box, 2-ch cls) + softmax + anchors + clip + mask.
// One thread per feature pixel.
__global__ __launch_bounds__(256) void head_kernel(
    const float* __restrict__ feats, const float* __restrict__ bw,
    const float* __restrict__ bb, const float* __restrict__ clw,
    const float* __restrict__ clb, float* __restrict__ out) {
    __shared__ float s_bw[648];  // [36][2][3][3]
    __shared__ float s_bb[36];
    __shared__ float s_cw[36];   // [2][2][3][3]
    __shared__ float s_cb[2];
    const int tid = threadIdx.x;
    for (int e = tid; e < 648; e += 256) s_bw[e] = bw[e];
    if (tid < 36) { s_bb[tid] = bb[tid]; s_cw[tid] = clw[tid]; }
    if (tid < 2) s_cb[tid] = clb[tid];
    __syncthreads();

    const int p = blockIdx.x * 256 + tid;   // [0, 43008)
    const int j = p % WF;
    const int rem = p / WF;
    const int y = rem % HF;
    const int n = rem / HF;

    float f0[3][3], f1[3][3];
#pragma unroll
    for (int dy = 0; dy < 3; ++dy) {
        int yy = y + dy - 1;
#pragma unroll
        for (int dx = 0; dx < 3; ++dx) {
            int xx = j + dx - 1;
            float2 v = make_float2(0.f, 0.f);
            if (yy >= 0 && yy < HF && xx >= 0 && xx < WF)
                v = ((const float2*)feats)[(n * HF + yy) * WF + xx];
            f0[dy][dx] = v.x;
            f1[dy][dx] = v.y;
        }
    }

    // cls conv + softmax over 2 channels (max-subtracted, same as jax.nn.softmax)
    float c0 = s_cb[0], c1 = s_cb[1];
#pragma unroll
    for (int ky = 0; ky < 3; ++ky)
#pragma unroll
        for (int kx = 0; kx < 3; ++kx) {
            int k = ky * 3 + kx;
            c0 = fmaf(f0[ky][kx], s_cw[k], c0);
            c0 = fmaf(f1[ky][kx], s_cw[9 + k], c0);
            c1 = fmaf(f0[ky][kx], s_cw[18 + k], c1);
            c1 = fmaf(f1[ky][kx], s_cw[27 + k], c1);
        }
    float mx = fmaxf(c0, c1);
    float e0 = expf(c0 - mx), e1 = expf(c1 - mx);
    float p1 = e1 / (e0 + e1);
    const float maskf = (p1 > 0.95f) ? 1.f : 0.f;

    const float gx = (j + 0.5f) * 50.f;
    const float gy = (y + 0.5f) * 50.f;
    // anchors: sizes {16,32,64} x ratios {0.5,1,2}; ws = s/sqrt(r), hs = s*sqrt(r)
    const float wsv[9] = {22.627417f, 16.f, 11.3137085f,
                          45.254834f, 32.f, 22.627417f,
                          90.509668f, 64.f, 45.254834f};
    const float hsv[9] = {11.3137085f, 16.f, 22.627417f,
                          22.627417f, 32.f, 45.254834f,
                          45.254834f, 64.f, 90.509668f};

    float4* outp = (float4*)out + (size_t)p * 9;
#pragma unroll
    for (int a = 0; a < 9; ++a) {
        float o[4];
#pragma unroll
        for (int c = 0; c < 4; ++c) {
            const int ch = a * 4 + c;                 // box channel
            const float* w = &s_bw[ch * 18];
            float acc = s_bb[ch];
#pragma unroll
            for (int ky = 0; ky < 3; ++ky)
#pragma unroll
                for (int kx = 0; kx < 3; ++kx) {
                    int k = ky * 3 + kx;
                    acc = fmaf(f0[ky][kx], w[k], acc);
                    acc = fmaf(f1[ky][kx], w[9 + k], acc);
                }
            o[c] = acc;
        }
        const float hw = 0.5f * wsv[a], hh = 0.5f * hsv[a];
        float x1 = fminf(fmaxf(gx - hw + o[0], 0.f), 3200.f);
        float y1 = fminf(fmaxf(gy - hh + o[1], 0.f), 4200.f);
        float x2 = fminf(fmaxf(gx + hw + o[2], 0.f), 3200.f);
        float y2 = fminf(fmaxf(gy + hh + o[3], 0.f), 4200.f);
        outp[a] = make_float4(x1 * maskf, y1 * maskf, x2 * maskf, y2 * maskf);
    }
}

extern "C" void kernel_launch(void* const* d_in, const int* in_sizes, int n_in,
                              void* d_out, int out_size, void* d_ws, size_t ws_size,
                              hipStream_t stream) {
    const float* X   = (const float*)d_in[0];
    const float* cw  = (const float*)d_in[1];
    const float* cb  = (const float*)d_in[2];
    const float* bw  = (const float*)d_in[3];
    const float* bb  = (const float*)d_in[4];
    const float* clw = (const float*)d_in[5];
    const float* clb = (const float*)d_in[6];
    float* out = (float*)d_out;
    float* feats = (float*)d_ws;  // [8][84][64] float2 = 344 KB

    // 43008 tiles, 4 waves/block -> 10752 blocks
    conv1_kernel<<<10752, 256, 0, stream>>>(X, cw, cb, feats);
    // 43008 pixels / 256 = 168 blocks
    head_kernel<<<168, 256, 0, stream>>>(feats, bw, bb, clw, clb, out);
}